// Round 10
// baseline (176.918 us; speedup 1.0000x reference)
//
#include <hip/hip_runtime.h>

#define CCOL 10
#define TPB 256
#define NBLOCKS 1024            // persistent; 4 blocks/CU (LDS: 40960 B/block = 160KiB/CU)

// Native vector type: __builtin_nontemporal_load requires scalar/native-vector pointee.
typedef float v4f __attribute__((ext_vector_type(4)));
#define NT(p) __builtin_nontemporal_load(p)   // NT path: bypass L2 allocation

__device__ __forceinline__ float horner9(const float c[9], float x) {
    float v = c[8];
#pragma unroll
    for (int i = 7; i >= 0; i--) v = fmaf(v, x, c[i]);
    return v;
}

#define EXP4(v, base)                          \
    e[(base) + 0] = horner9(ec, (v).x);        \
    e[(base) + 1] = horner9(ec, (v).y);        \
    e[(base) + 2] = horner9(ec, (v).z);        \
    e[(base) + 3] = horner9(ec, (v).w);

#define LOG4(tv, base)                                                    \
    {                                                                     \
        float i0 = ((base) + 0 < CCOL) ? inv0 : inv1;                     \
        float i1 = ((base) + 1 < CCOL) ? inv0 : inv1;                     \
        float i2 = ((base) + 2 < CCOL) ? inv0 : inv1;                     \
        float i3 = ((base) + 3 < CCOL) ? inv0 : inv1;                     \
        local = fmaf((tv).x, horner9(lc, e[(base) + 0] * i0), local);     \
        local = fmaf((tv).y, horner9(lc, e[(base) + 1] * i1), local);     \
        local = fmaf((tv).z, horner9(lc, e[(base) + 2] * i2), local);     \
        local = fmaf((tv).w, horner9(lc, e[(base) + 3] * i3), local);     \
    }

__global__ __launch_bounds__(TPB, 4) void ce_kernel(
    const float* __restrict__ x, const float* __restrict__ tgt,
    const float* __restrict__ exp_c, const float* __restrict__ inv_c,
    const float* __restrict__ log_c, const int* __restrict__ iters_p,
    float* __restrict__ partials, int npairs, int nchunks)
{
    // 4 waves * (320 x-v4f + 320 t-v4f) = 2560 v4f = 40960 B exactly.
    __shared__ v4f lds4[2560];

    float ec[9], ic[5], lc[9];
#pragma unroll
    for (int i = 0; i < 9; i++) ec[i] = exp_c[i];
#pragma unroll
    for (int i = 0; i < 5; i++) ic[i] = inv_c[i];
#pragma unroll
    for (int i = 0; i < 9; i++) lc[i] = log_c[i];
    const int niter = iters_p[0];

    const int tid  = threadIdx.x;
    const int lane = tid & 63;
    const int w    = tid >> 6;
    const int wg   = blockIdx.x * 4 + w;      // global wave id
    const int W    = gridDim.x * 4;           // total waves

    v4f* lx = lds4 + w * 640;
    v4f* lt = lx + 320;
    const v4f* bx = (const v4f*)((const float*)lx + lane * 20);
    const v4f* bt = (const v4f*)((const float*)lt + lane * 20);

    float local = 0.0f;

    // ---- depth-1 pipeline; x via NT path, t via cached path (split streams) ----
    int q = wg;
    v4f rx0, rx1, rx2, rx3, rx4, rt0, rt1, rt2, rt3, rt4;
    if (q < nchunks) {
        const v4f* gx = (const v4f*)x   + (size_t)q * 320 + lane;
        const v4f* gt = (const v4f*)tgt + (size_t)q * 320 + lane;
        rx0 = NT(gx); rx1 = NT(gx + 64); rx2 = NT(gx + 128); rx3 = NT(gx + 192); rx4 = NT(gx + 256);
        rt0 = gt[0];  rt1 = gt[64];      rt2 = gt[128];      rt3 = gt[192];      rt4 = gt[256];
    }

    while (q < nchunks) {
        // stage current chunk into wave-private LDS (wave-synchronous;
        // no __syncthreads in hot loop)
        v4f* sx = lx + lane;
        sx[0] = rx0; sx[64] = rx1; sx[128] = rx2; sx[192] = rx3; sx[256] = rx4;
        v4f* st = lt + lane;
        st[0] = rt0; st[64] = rt1; st[128] = rt2; st[192] = rt3; st[256] = rt4;

        // prefetch next chunk (stays in flight across compute)
        int qn = q + W;
        if (qn < nchunks) {
            const v4f* gx = (const v4f*)x   + (size_t)qn * 320 + lane;
            const v4f* gt = (const v4f*)tgt + (size_t)qn * 320 + lane;
            rx0 = NT(gx); rx1 = NT(gx + 64); rx2 = NT(gx + 128); rx3 = NT(gx + 192); rx4 = NT(gx + 256);
            rt0 = gt[0];  rt1 = gt[64];      rt2 = gt[128];      rt3 = gt[192];      rt4 = gt[256];
        }

        // ---- compute from LDS (stride 80 B, measured conflict-free) ----
        v4f a0 = bx[0], a1 = bx[1], a2 = bx[2], a3 = bx[3], a4 = bx[4];
        float e[2 * CCOL];
        EXP4(a0, 0) EXP4(a1, 4) EXP4(a2, 8) EXP4(a3, 12) EXP4(a4, 16)

        float s0 = 0.0f, s1 = 0.0f;
#pragma unroll
        for (int i = 0; i < CCOL; i++) s0 += e[i];
#pragma unroll
        for (int i = CCOL; i < 2 * CCOL; i++) s1 += e[i];

        float inv0 = ic[4], inv1 = ic[4];
#pragma unroll
        for (int k = 3; k >= 0; k--) {
            inv0 = fmaf(inv0, s0, ic[k]);
            inv1 = fmaf(inv1, s1, ic[k]);
        }
        for (int k = 0; k < niter; k++) {
            inv0 = inv0 * (2.0f - s0 * inv0);
            inv1 = inv1 * (2.0f - s1 * inv1);
        }

        v4f t0 = bt[0], t1 = bt[1], t2 = bt[2], t3 = bt[3], t4 = bt[4];
        LOG4(t0, 0) LOG4(t1, 4) LOG4(t2, 8) LOG4(t3, 12) LOG4(t4, 16)

        q = qn;
    }

    // ---- tail pairs (npairs % 64; zero for B=2e6) ----
    int tail0 = nchunks * 64;
    for (int p = tail0 + blockIdx.x * TPB + tid; p < npairs; p += gridDim.x * TPB) {
        const float* xp = x   + (size_t)p * 2 * CCOL;
        const float* tp = tgt + (size_t)p * 2 * CCOL;
#pragma unroll
        for (int r = 0; r < 2; r++) {
            float e2[CCOL], s = 0.0f;
#pragma unroll
            for (int c = 0; c < CCOL; c++) {
                float v = horner9(ec, xp[r * CCOL + c]);
                e2[c] = v; s += v;
            }
            float inv = ic[4];
#pragma unroll
            for (int k = 3; k >= 0; k--) inv = fmaf(inv, s, ic[k]);
            for (int k = 0; k < niter; k++) inv = inv * (2.0f - s * inv);
#pragma unroll
            for (int c = 0; c < CCOL; c++)
                local = fmaf(tp[r * CCOL + c], horner9(lc, e2[c] * inv), local);
        }
    }

    // ---- block reduction ----
#pragma unroll
    for (int off = 32; off > 0; off >>= 1)
        local += __shfl_down(local, off, 64);

    __syncthreads();
    float* wsum = (float*)lds4;
    if (lane == 0) wsum[w] = local;
    __syncthreads();
    if (tid == 0)
        partials[blockIdx.x] = wsum[0] + wsum[1] + wsum[2] + wsum[3];
}

__global__ __launch_bounds__(TPB) void reduce_kernel(
    const float* __restrict__ partials, float* __restrict__ out, float neg_inv_b)
{
    int tid = threadIdx.x;
    float local = 0.0f;
#pragma unroll
    for (int k = 0; k < NBLOCKS / TPB; k++)
        local += partials[tid + k * TPB];
#pragma unroll
    for (int off = 32; off > 0; off >>= 1)
        local += __shfl_down(local, off, 64);
    __shared__ float wsum[4];
    if ((tid & 63) == 0) wsum[tid >> 6] = local;
    __syncthreads();
    if (tid == 0)
        out[0] = (wsum[0] + wsum[1] + wsum[2] + wsum[3]) * neg_inv_b;
}

extern "C" void kernel_launch(void* const* d_in, const int* in_sizes, int n_in,
                              void* d_out, int out_size, void* d_ws, size_t ws_size,
                              hipStream_t stream) {
    const float* x  = (const float*)d_in[0];
    const float* t  = (const float*)d_in[1];
    const float* ec = (const float*)d_in[2];
    const float* ic = (const float*)d_in[3];
    const float* lc = (const float*)d_in[4];
    const int*   it = (const int*)d_in[5];
    float* out = (float*)d_out;
    float* partials = (float*)d_ws;          // NBLOCKS floats

    int b_rows = in_sizes[0] / CCOL;         // 2,000,000
    int npairs = b_rows / 2;                 // 1,000,000
    int nchunks = npairs / 64;               // 15,625 (exact, no tail)
    float neg_inv_b = -1.0f / (float)b_rows;

    ce_kernel<<<NBLOCKS, TPB, 0, stream>>>(x, t, ec, ic, lc, it, partials,
                                           npairs, nchunks);
    reduce_kernel<<<1, TPB, 0, stream>>>(partials, out, neg_inv_b);
}

// Round 11
// 167.797 us; speedup vs baseline: 1.0544x; 1.0544x over previous
//
#include <hip/hip_runtime.h>

#define CCOL 10
#define TPB 256
#define NBLOCKS 1024            // persistent; 4 blocks/CU (LDS: 40960 B/block = 160KiB/CU)

// Native vector type: __builtin_nontemporal_load requires scalar/native-vector
// pointee (HIP's float4 is a struct and is rejected). Same 16B layout/alignment.
typedef float v4f __attribute__((ext_vector_type(4)));
#define NT(p) __builtin_nontemporal_load(p)   // zero-reuse stream: bypass cache fill path
// NT on BOTH streams is the measured optimum (R8: ~3.5 TB/s read vs 2.6 cached,
// 2.9 mixed). Depth-2 prefetch (R9) and split cached/NT (R10) both falsified.

__device__ __forceinline__ float horner9(const float c[9], float x) {
    float v = c[8];
#pragma unroll
    for (int i = 7; i >= 0; i--) v = fmaf(v, x, c[i]);
    return v;
}

// exp-poly one v4f -> e[base..base+3]
#define EXP4(v, base)                          \
    e[(base) + 0] = horner9(ec, (v).x);        \
    e[(base) + 1] = horner9(ec, (v).y);        \
    e[(base) + 2] = horner9(ec, (v).z);        \
    e[(base) + 3] = horner9(ec, (v).w);

// log-poly + dot with target for one v4f (constant base -> inv select folds)
#define LOG4(tv, base)                                                    \
    {                                                                     \
        float i0 = ((base) + 0 < CCOL) ? inv0 : inv1;                     \
        float i1 = ((base) + 1 < CCOL) ? inv0 : inv1;                     \
        float i2 = ((base) + 2 < CCOL) ? inv0 : inv1;                     \
        float i3 = ((base) + 3 < CCOL) ? inv0 : inv1;                     \
        local = fmaf((tv).x, horner9(lc, e[(base) + 0] * i0), local);     \
        local = fmaf((tv).y, horner9(lc, e[(base) + 1] * i1), local);     \
        local = fmaf((tv).z, horner9(lc, e[(base) + 2] * i2), local);     \
        local = fmaf((tv).w, horner9(lc, e[(base) + 3] * i3), local);     \
    }

__global__ __launch_bounds__(TPB, 4) void ce_kernel(
    const float* __restrict__ x, const float* __restrict__ tgt,
    const float* __restrict__ exp_c, const float* __restrict__ inv_c,
    const float* __restrict__ log_c, const int* __restrict__ iters_p,
    float* __restrict__ partials, int npairs, int nchunks)
{
    // 4 waves * (320 x-v4f + 320 t-v4f) = 2560 v4f = 40960 B exactly.
    __shared__ v4f lds4[2560];

    // Coefficients: uniform -> SGPR broadcast (cached loads kept here).
    float ec[9], ic[5], lc[9];
#pragma unroll
    for (int i = 0; i < 9; i++) ec[i] = exp_c[i];
#pragma unroll
    for (int i = 0; i < 5; i++) ic[i] = inv_c[i];
#pragma unroll
    for (int i = 0; i < 9; i++) lc[i] = log_c[i];
    const int niter = iters_p[0];

    const int tid  = threadIdx.x;
    const int lane = tid & 63;
    const int w    = tid >> 6;
    const int wg   = blockIdx.x * 4 + w;      // global wave id
    const int W    = gridDim.x * 4;           // total waves

    v4f* lx = lds4 + w * 640;                 // this wave's x region (320 v4f)
    v4f* lt = lx + 320;                       // this wave's t region
    const v4f* bx = (const v4f*)((const float*)lx + lane * 20);  // lane's pair, 16B-aligned
    const v4f* bt = (const v4f*)((const float*)lt + lane * 20);

    float local = 0.0f;

    // ---- wave-private pipelined loop: chunk = 64 pairs = 5120 B per array ----
    // Prefetch in NAMED v4f regs (no alloca -> no scratch), NT loads (no cache fill).
    int q = wg;
    v4f rx0, rx1, rx2, rx3, rx4, rt0, rt1, rt2, rt3, rt4;
    if (q < nchunks) {
        const v4f* gx = (const v4f*)x   + (size_t)q * 320 + lane;
        const v4f* gt = (const v4f*)tgt + (size_t)q * 320 + lane;
        rx0 = NT(gx); rx1 = NT(gx + 64); rx2 = NT(gx + 128); rx3 = NT(gx + 192); rx4 = NT(gx + 256);
        rt0 = NT(gt); rt1 = NT(gt + 64); rt2 = NT(gt + 128); rt3 = NT(gt + 192); rt4 = NT(gt + 256);
    }

    while (q < nchunks) {
        // stage current chunk into wave-private LDS (wave-synchronous transpose;
        // no __syncthreads in hot loop -> no block-wide vmcnt(0) drain)
        v4f* sx = lx + lane;
        sx[0] = rx0; sx[64] = rx1; sx[128] = rx2; sx[192] = rx3; sx[256] = rx4;
        v4f* st = lt + lane;
        st[0] = rt0; st[64] = rt1; st[128] = rt2; st[192] = rt3; st[256] = rt4;

        // prefetch next chunk (stays in flight across compute)
        int qn = q + W;
        if (qn < nchunks) {
            const v4f* gx = (const v4f*)x   + (size_t)qn * 320 + lane;
            const v4f* gt = (const v4f*)tgt + (size_t)qn * 320 + lane;
            rx0 = NT(gx); rx1 = NT(gx + 64); rx2 = NT(gx + 128); rx3 = NT(gx + 192); rx4 = NT(gx + 256);
            rt0 = NT(gt); rt1 = NT(gt + 64); rt2 = NT(gt + 128); rt3 = NT(gt + 192); rt4 = NT(gt + 256);
        }

        // ---- compute: lane's own pair from LDS (stride 80 B, 0 conflicts measured) ----
        v4f a0 = bx[0], a1 = bx[1], a2 = bx[2], a3 = bx[3], a4 = bx[4];
        float e[2 * CCOL];
        EXP4(a0, 0) EXP4(a1, 4) EXP4(a2, 8) EXP4(a3, 12) EXP4(a4, 16)

        float s0 = 0.0f, s1 = 0.0f;
#pragma unroll
        for (int i = 0; i < CCOL; i++) s0 += e[i];
#pragma unroll
        for (int i = CCOL; i < 2 * CCOL; i++) s1 += e[i];

        float inv0 = ic[4], inv1 = ic[4];
#pragma unroll
        for (int k = 3; k >= 0; k--) {
            inv0 = fmaf(inv0, s0, ic[k]);
            inv1 = fmaf(inv1, s1, ic[k]);
        }
        for (int k = 0; k < niter; k++) {
            inv0 = inv0 * (2.0f - s0 * inv0);
            inv1 = inv1 * (2.0f - s1 * inv1);
        }

        v4f t0 = bt[0], t1 = bt[1], t2 = bt[2], t3 = bt[3], t4 = bt[4];
        LOG4(t0, 0) LOG4(t1, 4) LOG4(t2, 8) LOG4(t3, 12) LOG4(t4, 16)

        q = qn;
    }

    // ---- tail pairs (npairs % 64; zero for B=2e6) ----
    int tail0 = nchunks * 64;
    for (int p = tail0 + blockIdx.x * TPB + tid; p < npairs; p += gridDim.x * TPB) {
        const float* xp = x   + (size_t)p * 2 * CCOL;
        const float* tp = tgt + (size_t)p * 2 * CCOL;
#pragma unroll
        for (int r = 0; r < 2; r++) {
            float e2[CCOL], s = 0.0f;
#pragma unroll
            for (int c = 0; c < CCOL; c++) {
                float v = horner9(ec, xp[r * CCOL + c]);
                e2[c] = v; s += v;
            }
            float inv = ic[4];
#pragma unroll
            for (int k = 3; k >= 0; k--) inv = fmaf(inv, s, ic[k]);
            for (int k = 0; k < niter; k++) inv = inv * (2.0f - s * inv);
#pragma unroll
            for (int c = 0; c < CCOL; c++)
                local = fmaf(tp[r * CCOL + c], horner9(lc, e2[c] * inv), local);
        }
    }

    // ---- block reduction: shuffle -> LDS (reused post-barrier) -> one write ----
#pragma unroll
    for (int off = 32; off > 0; off >>= 1)
        local += __shfl_down(local, off, 64);

    __syncthreads();                          // all waves done with staging LDS
    float* wsum = (float*)lds4;
    if (lane == 0) wsum[w] = local;
    __syncthreads();
    if (tid == 0)
        partials[blockIdx.x] = wsum[0] + wsum[1] + wsum[2] + wsum[3];
}

__global__ __launch_bounds__(TPB) void reduce_kernel(
    const float* __restrict__ partials, float* __restrict__ out, float neg_inv_b)
{
    int tid = threadIdx.x;
    float local = 0.0f;
#pragma unroll
    for (int k = 0; k < NBLOCKS / TPB; k++)
        local += partials[tid + k * TPB];
#pragma unroll
    for (int off = 32; off > 0; off >>= 1)
        local += __shfl_down(local, off, 64);
    __shared__ float wsum[4];
    if ((tid & 63) == 0) wsum[tid >> 6] = local;
    __syncthreads();
    if (tid == 0)
        out[0] = (wsum[0] + wsum[1] + wsum[2] + wsum[3]) * neg_inv_b;
}

extern "C" void kernel_launch(void* const* d_in, const int* in_sizes, int n_in,
                              void* d_out, int out_size, void* d_ws, size_t ws_size,
                              hipStream_t stream) {
    const float* x  = (const float*)d_in[0];
    const float* t  = (const float*)d_in[1];
    const float* ec = (const float*)d_in[2];
    const float* ic = (const float*)d_in[3];
    const float* lc = (const float*)d_in[4];
    const int*   it = (const int*)d_in[5];
    float* out = (float*)d_out;
    float* partials = (float*)d_ws;          // NBLOCKS floats

    int b_rows = in_sizes[0] / CCOL;         // 2,000,000
    int npairs = b_rows / 2;                 // 1,000,000
    int nchunks = npairs / 64;               // 15,625 (exact, no tail)
    float neg_inv_b = -1.0f / (float)b_rows;

    ce_kernel<<<NBLOCKS, TPB, 0, stream>>>(x, t, ec, ic, lc, it, partials,
                                           npairs, nchunks);
    reduce_kernel<<<1, TPB, 0, stream>>>(partials, out, neg_inv_b);
}